// Round 1
// baseline (25600.522 us; speedup 1.0000x reference)
//
#include <hip/hip_runtime.h>
#include <hip/hip_bf16.h>
#include <math.h>

#define N_LAYERS 4
#define NHEADS 16
#define LOOKBACK 128

// ---------------- block reductions (blockDim == 256, 4 waves) ----------------
__device__ __forceinline__ float blk_max(float v, volatile float* red) {
#pragma unroll
    for (int o = 32; o > 0; o >>= 1) v = fmaxf(v, __shfl_down(v, o, 64));
    if ((threadIdx.x & 63) == 0) red[threadIdx.x >> 6] = v;
    __syncthreads();
    float r = fmaxf(fmaxf(red[0], red[1]), fmaxf(red[2], red[3]));
    __syncthreads();
    return r;
}
__device__ __forceinline__ float blk_sum(float v, volatile float* red) {
#pragma unroll
    for (int o = 32; o > 0; o >>= 1) v += __shfl_down(v, o, 64);
    if ((threadIdx.x & 63) == 0) red[threadIdx.x >> 6] = v;
    __syncthreads();
    float r = red[0] + red[1] + red[2] + red[3];
    __syncthreads();
    return r;
}

// ---------------- RMSNorm: one block per row ----------------
__global__ __launch_bounds__(256) void rmsnorm_k(const float* __restrict__ x,
                                                 const float* __restrict__ w,
                                                 float* __restrict__ out, int D) {
    __shared__ float red[4];
    size_t row = blockIdx.x;
    const float* xr = x + row * D;
    float ss = 0.f;
    for (int i = threadIdx.x; i < D; i += 256) { float v = xr[i]; ss += v * v; }
    float tot = blk_sum(ss, red);
    float r = rsqrtf(tot / (float)D + 1e-6f);
    float* o = out + row * D;
    for (int i = threadIdx.x; i < D; i += 256) o[i] = xr[i] * r * w[i];
}

// ---------------- NT GEMM: C[m,n] = sum_k A[m,k] * Bw[n,k]  (+epilogues) ----
// M,N multiples of 64; K multiple of 16 (true for all shapes here).
#define BM 64
#define BN 64
#define BKK 16
#define LDT (BM + 4)

__global__ __launch_bounds__(256) void gemm_nt(
    const float* __restrict__ A, const float* __restrict__ Bw,
    float* __restrict__ C, const float* __restrict__ bias,
    const float* __restrict__ resid, const float* __restrict__ aux,
    int M, int N, int K) {
    __shared__ float As[BKK][LDT];
    __shared__ float Bs[BKK][LDT];
    int tid = threadIdx.x;
    int tm = (tid >> 4) << 2;   // 0..60
    int tn = (tid & 15) << 2;   // 0..60
    size_t bm = (size_t)blockIdx.y * BM;
    size_t bn = (size_t)blockIdx.x * BN;
    int lrow = tid >> 2;        // 0..63
    int lk = (tid & 3) << 2;    // 0,4,8,12
    const float* aptr = A + (bm + lrow) * K + lk;
    const float* bptr = Bw + (bn + lrow) * K + lk;
    float acc[4][4] = {};
    for (int k0 = 0; k0 < K; k0 += BKK) {
        float4 av = *(const float4*)(aptr + k0);
        float4 bv = *(const float4*)(bptr + k0);
        As[lk + 0][lrow] = av.x; As[lk + 1][lrow] = av.y;
        As[lk + 2][lrow] = av.z; As[lk + 3][lrow] = av.w;
        Bs[lk + 0][lrow] = bv.x; Bs[lk + 1][lrow] = bv.y;
        Bs[lk + 2][lrow] = bv.z; Bs[lk + 3][lrow] = bv.w;
        __syncthreads();
#pragma unroll
        for (int k = 0; k < BKK; ++k) {
            float a0 = As[k][tm + 0], a1 = As[k][tm + 1], a2 = As[k][tm + 2], a3 = As[k][tm + 3];
            float b0 = Bs[k][tn + 0], b1 = Bs[k][tn + 1], b2 = Bs[k][tn + 2], b3 = Bs[k][tn + 3];
            acc[0][0] += a0 * b0; acc[0][1] += a0 * b1; acc[0][2] += a0 * b2; acc[0][3] += a0 * b3;
            acc[1][0] += a1 * b0; acc[1][1] += a1 * b1; acc[1][2] += a1 * b2; acc[1][3] += a1 * b3;
            acc[2][0] += a2 * b0; acc[2][1] += a2 * b1; acc[2][2] += a2 * b2; acc[2][3] += a2 * b3;
            acc[3][0] += a3 * b0; acc[3][1] += a3 * b1; acc[3][2] += a3 * b2; acc[3][3] += a3 * b3;
        }
        __syncthreads();
    }
#pragma unroll
    for (int i = 0; i < 4; ++i) {
        size_t m = bm + tm + i;
#pragma unroll
        for (int j = 0; j < 4; ++j) {
            size_t n = bn + tn + j;
            float v = acc[i][j];
            if (bias) v += bias[n];
            if (aux) { float g = aux[m * N + n]; v *= g / (1.0f + __expf(-g)); }
            if (resid) v += resid[m * N + n];
            C[m * N + n] = v;
        }
    }
}

// ---------------- RoPE in place on q and k of qkv buffer ----------------
__global__ void rope_k(float* __restrict__ qkv, int L, int total) {
    int idx = blockIdx.x * 256 + threadIdx.x;
    if (idx >= total) return;
    int d = idx & 31;
    int h = (idx >> 5) & 15;
    int bl = idx >> 9;
    int l = bl % L;
    float inv = powf(10000.0f, -(float)d * (1.0f / 32.0f));
    float f = (float)l * inv;
    float s, c;
    sincosf(f, &s, &c);
    float* base = qkv + (size_t)bl * 3072 + h * 64 + d;
    float x1 = base[0], x2 = base[32];
    base[0] = x1 * c - x2 * s;
    base[32] = x2 * c + x1 * s;
    float* kb = base + 1024;
    x1 = kb[0]; x2 = kb[32];
    kb[0] = x1 * c - x2 * s;
    kb[32] = x2 * c + x1 * s;
}

// ---------------- causal self-attention: one block per (b,h,l) ----------------
__global__ __launch_bounds__(256) void self_attn_k(
    const float* __restrict__ qkv, float* __restrict__ out, int L) {
    int l = blockIdx.x, h = blockIdx.y, b = blockIdx.z;
    __shared__ float qs[64];
    __shared__ float sc[2048];
    __shared__ float red[4];
    __shared__ float pv[4][64];
    int tid = threadIdx.x;
    size_t rowbase = ((size_t)b * L + l) * 3072;
    if (tid < 64) qs[tid] = qkv[rowbase + h * 64 + tid];
    __syncthreads();
    int nk = l + 1;
    float lmax = -1e30f;
    for (int k = tid; k < nk; k += 256) {
        const float* kr = qkv + ((size_t)b * L + k) * 3072 + 1024 + h * 64;
        float s = 0.f;
#pragma unroll
        for (int d = 0; d < 64; d += 4) {
            float4 k4 = *(const float4*)(kr + d);
            s += qs[d] * k4.x + qs[d + 1] * k4.y + qs[d + 2] * k4.z + qs[d + 3] * k4.w;
        }
        s *= 0.125f;
        sc[k] = s;
        lmax = fmaxf(lmax, s);
    }
    float gmax = blk_max(lmax, red);
    float lsum = 0.f;
    for (int k = tid; k < nk; k += 256) {
        float p = __expf(sc[k] - gmax);
        sc[k] = p;
        lsum += p;
    }
    float gsum = blk_sum(lsum, red);
    float inv = 1.0f / gsum;
    int d = tid & 63, part = tid >> 6;
    float acc = 0.f;
    for (int k = part; k < nk; k += 4)
        acc += sc[k] * qkv[((size_t)b * L + k) * 3072 + 2048 + h * 64 + d];
    pv[part][d] = acc;
    __syncthreads();
    if (tid < 64) {
        float r = (pv[0][tid] + pv[1][tid] + pv[2][tid] + pv[3][tid]) * inv;
        out[((size_t)b * L + l) * 1024 + h * 64 + tid] = r;
    }
}

// ---------------- cross-attention: window (seg-128, seg] over memory --------
__global__ __launch_bounds__(256) void cross_attn_k(
    const float* __restrict__ qc, const float* __restrict__ kv,
    const int* __restrict__ seg_ids, float* __restrict__ out, int L, int S) {
    int l = blockIdx.x, h = blockIdx.y, b = blockIdx.z;
    __shared__ float qs[64];
    __shared__ float sc[LOOKBACK];
    __shared__ float red[4];
    __shared__ float pv[4][64];
    int tid = threadIdx.x;
    int seg = seg_ids[(size_t)b * L + l];
    int k0 = seg - LOOKBACK + 1; if (k0 < 0) k0 = 0;
    int nk = seg - k0 + 1;  // <= 128
    if (tid < 64) qs[tid] = qc[((size_t)b * L + l) * 1024 + h * 64 + tid];
    __syncthreads();
    float lmax = -1e30f;
    if (tid < nk) {
        int k = k0 + tid;
        const float* kr = kv + ((size_t)b * S + k) * 2048 + h * 64;
        float s = 0.f;
#pragma unroll
        for (int d = 0; d < 64; d += 4) {
            float4 k4 = *(const float4*)(kr + d);
            s += qs[d] * k4.x + qs[d + 1] * k4.y + qs[d + 2] * k4.z + qs[d + 3] * k4.w;
        }
        s *= 0.125f;
        sc[tid] = s;
        lmax = s;
    }
    float gmax = blk_max(lmax, red);
    float lsum = 0.f;
    if (tid < nk) {
        float p = __expf(sc[tid] - gmax);
        sc[tid] = p;
        lsum = p;
    }
    float gsum = blk_sum(lsum, red);
    float inv = 1.0f / gsum;
    int d = tid & 63, part = tid >> 6;
    float acc = 0.f;
    for (int kk = part; kk < nk; kk += 4)
        acc += sc[kk] * kv[((size_t)b * S + k0 + kk) * 2048 + 1024 + h * 64 + d];
    pv[part][d] = acc;
    __syncthreads();
    if (tid < 64) {
        float r = (pv[0][tid] + pv[1][tid] + pv[2][tid] + pv[3][tid]) * inv;
        out[((size_t)b * L + l) * 1024 + h * 64 + tid] = r;
    }
}

// ---------------- driver ----------------
extern "C" void kernel_launch(void* const* d_in, const int* in_sizes, int n_in,
                              void* d_out, int out_size, void* d_ws, size_t ws_size,
                              hipStream_t stream) {
    const int B = 2, L = 2048, S = 256, D = 1024, F = 4096;
    const int BL = B * L;
    const float* x_in   = (const float*)d_in[0];
    const float* memory = (const float*)d_in[1];
    const int*   seg    = (const int*)d_in[2];
    const float* Wqkv = (const float*)d_in[3];
    const float* bqkv = (const float*)d_in[4];
    const float* Wo   = (const float*)d_in[5];
    const float* bo   = (const float*)d_in[6];
    const float* Wq_c = (const float*)d_in[7];
    const float* Wkv_c= (const float*)d_in[8];
    const float* Wo_c = (const float*)d_in[9];
    const float* Wg   = (const float*)d_in[10];
    const float* Wu   = (const float*)d_in[11];
    const float* Wd   = (const float*)d_in[12];
    const float* n1   = (const float*)d_in[13];
    const float* n2   = (const float*)d_in[14];
    const float* n3   = (const float*)d_in[15];
    const float* nf   = (const float*)d_in[16];

    float* ws = (float*)d_ws;
    size_t off = 0;
    float* X   = ws + off; off += (size_t)BL * D;
    float* Hb  = ws + off; off += (size_t)BL * D;
    float* Att = ws + off; off += (size_t)BL * D;
    float* KVC = ws + off; off += (size_t)B * S * 2 * D;
    float* BIG = ws + off; off += (size_t)BL * F;  // QKV (BL*3D) aliases G (BL*F)
    float* QKV = BIG;
    float* G   = BIG;

    hipMemcpyAsync(X, x_in, (size_t)BL * D * sizeof(float), hipMemcpyDeviceToDevice, stream);

    dim3 blk(256);
    for (int l = 0; l < N_LAYERS; ++l) {
        // ---- self-attention block ----
        rmsnorm_k<<<BL, blk, 0, stream>>>(X, n1 + (size_t)l * D, Hb, D);
        gemm_nt<<<dim3(3 * D / 64, BL / 64), blk, 0, stream>>>(
            Hb, Wqkv + (size_t)l * 3 * D * D, QKV, bqkv + (size_t)l * 3 * D,
            nullptr, nullptr, BL, 3 * D, D);
        int total = BL * NHEADS * 32;
        rope_k<<<(total + 255) / 256, blk, 0, stream>>>(QKV, L, total);
        self_attn_k<<<dim3(L, NHEADS, B), blk, 0, stream>>>(QKV, Att, L);
        gemm_nt<<<dim3(D / 64, BL / 64), blk, 0, stream>>>(
            Att, Wo + (size_t)l * D * D, X, bo + (size_t)l * D, X, nullptr, BL, D, D);
        // ---- cross-attention block ----
        rmsnorm_k<<<BL, blk, 0, stream>>>(X, n2 + (size_t)l * D, Hb, D);
        gemm_nt<<<dim3(D / 64, BL / 64), blk, 0, stream>>>(
            Hb, Wq_c + (size_t)l * D * D, Att, nullptr, nullptr, nullptr, BL, D, D);
        gemm_nt<<<dim3(2 * D / 64, B * S / 64), blk, 0, stream>>>(
            memory, Wkv_c + (size_t)l * 2 * D * D, KVC, nullptr, nullptr, nullptr, B * S, 2 * D, D);
        cross_attn_k<<<dim3(L, NHEADS, B), blk, 0, stream>>>(Att, KVC, seg, Hb, L, S);
        gemm_nt<<<dim3(D / 64, BL / 64), blk, 0, stream>>>(
            Hb, Wo_c + (size_t)l * D * D, X, nullptr, X, nullptr, BL, D, D);
        // ---- MLP (SwiGLU) ----
        rmsnorm_k<<<BL, blk, 0, stream>>>(X, n3 + (size_t)l * D, Hb, D);
        gemm_nt<<<dim3(F / 64, BL / 64), blk, 0, stream>>>(
            Hb, Wg + (size_t)l * F * D, G, nullptr, nullptr, nullptr, BL, F, D);
        gemm_nt<<<dim3(F / 64, BL / 64), blk, 0, stream>>>(
            Hb, Wu + (size_t)l * F * D, G, nullptr, nullptr, G, BL, F, D);
        gemm_nt<<<dim3(D / 64, BL / 64), blk, 0, stream>>>(
            G, Wd + (size_t)l * D * F, X, nullptr, X, nullptr, BL, D, F);
    }
    rmsnorm_k<<<BL, blk, 0, stream>>>(X, nf, (float*)d_out, D);
}

// Round 2
// 14744.331 us; speedup vs baseline: 1.7363x; 1.7363x over previous
//
#include <hip/hip_runtime.h>
#include <hip/hip_bf16.h>
#include <math.h>

#define N_LAYERS 4
#define NHEADS 16
#define LOOKBACK 128

// ---------------- block reductions (blockDim == 256, 4 waves) ----------------
__device__ __forceinline__ float blk_max(float v, volatile float* red) {
#pragma unroll
    for (int o = 32; o > 0; o >>= 1) v = fmaxf(v, __shfl_down(v, o, 64));
    if ((threadIdx.x & 63) == 0) red[threadIdx.x >> 6] = v;
    __syncthreads();
    float r = fmaxf(fmaxf(red[0], red[1]), fmaxf(red[2], red[3]));
    __syncthreads();
    return r;
}
__device__ __forceinline__ float blk_sum(float v, volatile float* red) {
#pragma unroll
    for (int o = 32; o > 0; o >>= 1) v += __shfl_down(v, o, 64);
    if ((threadIdx.x & 63) == 0) red[threadIdx.x >> 6] = v;
    __syncthreads();
    float r = red[0] + red[1] + red[2] + red[3];
    __syncthreads();
    return r;
}

// ---------------- RMSNorm: one block per row ----------------
__global__ __launch_bounds__(256) void rmsnorm_k(const float* __restrict__ x,
                                                 const float* __restrict__ w,
                                                 float* __restrict__ out, int D) {
    __shared__ float red[4];
    size_t row = blockIdx.x;
    const float* xr = x + row * D;
    float ss = 0.f;
    for (int i = threadIdx.x; i < D; i += 256) { float v = xr[i]; ss += v * v; }
    float tot = blk_sum(ss, red);
    float r = rsqrtf(tot / (float)D + 1e-6f);
    float* o = out + row * D;
    for (int i = threadIdx.x; i < D; i += 256) o[i] = xr[i] * r * w[i];
}

// ---------------- NT GEMM: C[m,n] = sum_k A[m,k] * Bw[n,k]  (+epilogues) ----
#define BM 64
#define BN 64
#define BKK 16
#define LDT (BM + 4)

__global__ __launch_bounds__(256) void gemm_nt(
    const float* __restrict__ A, const float* __restrict__ Bw,
    float* __restrict__ C, const float* __restrict__ bias,
    const float* __restrict__ resid, const float* __restrict__ aux,
    int M, int N, int K) {
    __shared__ float As[BKK][LDT];
    __shared__ float Bs[BKK][LDT];
    int tid = threadIdx.x;
    int tm = (tid >> 4) << 2;
    int tn = (tid & 15) << 2;
    size_t bm = (size_t)blockIdx.y * BM;
    size_t bn = (size_t)blockIdx.x * BN;
    int lrow = tid >> 2;
    int lk = (tid & 3) << 2;
    const float* aptr = A + (bm + lrow) * K + lk;
    const float* bptr = Bw + (bn + lrow) * K + lk;
    float acc[4][4] = {};
    for (int k0 = 0; k0 < K; k0 += BKK) {
        float4 av = *(const float4*)(aptr + k0);
        float4 bv = *(const float4*)(bptr + k0);
        As[lk + 0][lrow] = av.x; As[lk + 1][lrow] = av.y;
        As[lk + 2][lrow] = av.z; As[lk + 3][lrow] = av.w;
        Bs[lk + 0][lrow] = bv.x; Bs[lk + 1][lrow] = bv.y;
        Bs[lk + 2][lrow] = bv.z; Bs[lk + 3][lrow] = bv.w;
        __syncthreads();
#pragma unroll
        for (int k = 0; k < BKK; ++k) {
            float a0 = As[k][tm + 0], a1 = As[k][tm + 1], a2 = As[k][tm + 2], a3 = As[k][tm + 3];
            float b0 = Bs[k][tn + 0], b1 = Bs[k][tn + 1], b2 = Bs[k][tn + 2], b3 = Bs[k][tn + 3];
            acc[0][0] += a0 * b0; acc[0][1] += a0 * b1; acc[0][2] += a0 * b2; acc[0][3] += a0 * b3;
            acc[1][0] += a1 * b0; acc[1][1] += a1 * b1; acc[1][2] += a1 * b2; acc[1][3] += a1 * b3;
            acc[2][0] += a2 * b0; acc[2][1] += a2 * b1; acc[2][2] += a2 * b2; acc[2][3] += a2 * b3;
            acc[3][0] += a3 * b0; acc[3][1] += a3 * b1; acc[3][2] += a3 * b2; acc[3][3] += a3 * b3;
        }
        __syncthreads();
    }
#pragma unroll
    for (int i = 0; i < 4; ++i) {
        size_t m = bm + tm + i;
#pragma unroll
        for (int j = 0; j < 4; ++j) {
            size_t n = bn + tn + j;
            float v = acc[i][j];
            if (bias) v += bias[n];
            if (aux) { float g = aux[m * N + n]; v *= g / (1.0f + __expf(-g)); }
            if (resid) v += resid[m * N + n];
            C[m * N + n] = v;
        }
    }
}

// ---------------- RoPE in place on q and k of qkv buffer ----------------
__global__ void rope_k(float* __restrict__ qkv, int L, int total) {
    int idx = blockIdx.x * 256 + threadIdx.x;
    if (idx >= total) return;
    int d = idx & 31;
    int h = (idx >> 5) & 15;
    int bl = idx >> 9;
    int l = bl % L;
    float inv = powf(10000.0f, -(float)d * (1.0f / 32.0f));
    float f = (float)l * inv;
    float s, c;
    sincosf(f, &s, &c);
    float* base = qkv + (size_t)bl * 3072 + h * 64 + d;
    float x1 = base[0], x2 = base[32];
    base[0] = x1 * c - x2 * s;
    base[32] = x2 * c + x1 * s;
    float* kb = base + 1024;
    x1 = kb[0]; x2 = kb[32];
    kb[0] = x1 * c - x2 * s;
    kb[32] = x2 * c + x1 * s;
}

// ---------------- flash self-attention: 64q x 64k tiles ----------------
// grid: (L/64, H, B), block 256.
#define SPAD 68

__global__ __launch_bounds__(256) void self_attn_flash(
    const float* __restrict__ qkv, float* __restrict__ out, int L) {
    int qt = blockIdx.x, h = blockIdx.y, b = blockIdx.z;
    int q0 = qt * 64;
    __shared__ float Qs[64][SPAD];
    __shared__ float Ks[64][SPAD];
    __shared__ float VsT[64][SPAD];   // transposed: VsT[n][k]
    __shared__ float Ss[64][SPAD];
    __shared__ float mrow[64], lrow[64], arow[64];
    int tid = threadIdx.x;
    int lr = tid >> 2;          // staging row 0..63
    int lc = tid & 3;           // staging chunk 0..3
    // load Q tile (pre-scaled)
    {
        const float* src = qkv + ((size_t)b * L + q0 + lr) * 3072 + h * 64;
#pragma unroll
        for (int t = 0; t < 4; ++t) {
            int c = (lc + t * 4) * 4;
            float4 v = *(const float4*)(src + c);
            Qs[lr][c + 0] = v.x * 0.125f; Qs[lr][c + 1] = v.y * 0.125f;
            Qs[lr][c + 2] = v.z * 0.125f; Qs[lr][c + 3] = v.w * 0.125f;
        }
    }
    if (tid < 64) { mrow[tid] = -1e30f; lrow[tid] = 0.f; }
    int tm = tid >> 4;    // 0..15: rows tm+16i
    int tn = tid & 15;    // 0..15: cols tn+16j
    float acc[4][4] = {};
    for (int kt = 0; kt <= qt; ++kt) {
        int k0 = kt * 64;
        __syncthreads();
        // stage K (row-major) and V (transposed)
        {
            const float* ksrc = qkv + ((size_t)b * L + k0 + lr) * 3072 + 1024 + h * 64;
            const float* vsrc = ksrc + 1024;
#pragma unroll
            for (int t = 0; t < 4; ++t) {
                int c = (lc + t * 4) * 4;
                float4 kv4 = *(const float4*)(ksrc + c);
                Ks[lr][c + 0] = kv4.x; Ks[lr][c + 1] = kv4.y;
                Ks[lr][c + 2] = kv4.z; Ks[lr][c + 3] = kv4.w;
                float4 vv4 = *(const float4*)(vsrc + c);
                VsT[c + 0][lr] = vv4.x; VsT[c + 1][lr] = vv4.y;
                VsT[c + 2][lr] = vv4.z; VsT[c + 3][lr] = vv4.w;
            }
        }
        __syncthreads();
        // S = Q K^T (4x4 microtile, b128 along k)
        float s[4][4] = {};
        for (int k4 = 0; k4 < 64; k4 += 4) {
            float4 qv[4], kv[4];
#pragma unroll
            for (int i = 0; i < 4; ++i) qv[i] = *(const float4*)&Qs[tm + 16 * i][k4];
#pragma unroll
            for (int j = 0; j < 4; ++j) kv[j] = *(const float4*)&Ks[tn + 16 * j][k4];
#pragma unroll
            for (int i = 0; i < 4; ++i)
#pragma unroll
                for (int j = 0; j < 4; ++j)
                    s[i][j] += qv[i].x * kv[j].x + qv[i].y * kv[j].y +
                               qv[i].z * kv[j].z + qv[i].w * kv[j].w;
        }
        bool diag = (kt == qt);
#pragma unroll
        for (int i = 0; i < 4; ++i)
#pragma unroll
            for (int j = 0; j < 4; ++j) {
                float v = s[i][j];
                if (diag && (tn + 16 * j > tm + 16 * i)) v = -1e30f;
                Ss[tm + 16 * i][tn + 16 * j] = v;
            }
        __syncthreads();
        // online softmax, one thread per row
        if (tid < 64) {
            float mold = mrow[tid];
            float mx = mold;
            float* srow = &Ss[tid][0];
            for (int c = 0; c < 64; c += 4) {
                float4 v = *(const float4*)(srow + c);
                mx = fmaxf(mx, fmaxf(fmaxf(v.x, v.y), fmaxf(v.z, v.w)));
            }
            float al = __expf(mold - mx);
            float sum = 0.f;
            for (int c = 0; c < 64; c += 4) {
                float4 v = *(const float4*)(srow + c);
                v.x = __expf(v.x - mx); v.y = __expf(v.y - mx);
                v.z = __expf(v.z - mx); v.w = __expf(v.w - mx);
                sum += v.x + v.y + v.z + v.w;
                *(float4*)(srow + c) = v;
            }
            mrow[tid] = mx;
            lrow[tid] = lrow[tid] * al + sum;
            arow[tid] = al;
        }
        __syncthreads();
#pragma unroll
        for (int i = 0; i < 4; ++i) {
            float al = arow[tm + 16 * i];
#pragma unroll
            for (int j = 0; j < 4; ++j) acc[i][j] *= al;
        }
        // O += P V (b128 along k on both operands)
        for (int k4 = 0; k4 < 64; k4 += 4) {
            float4 pv[4], vv[4];
#pragma unroll
            for (int i = 0; i < 4; ++i) pv[i] = *(const float4*)&Ss[tm + 16 * i][k4];
#pragma unroll
            for (int j = 0; j < 4; ++j) vv[j] = *(const float4*)&VsT[tn + 16 * j][k4];
#pragma unroll
            for (int i = 0; i < 4; ++i)
#pragma unroll
                for (int j = 0; j < 4; ++j)
                    acc[i][j] += pv[i].x * vv[j].x + pv[i].y * vv[j].y +
                                 pv[i].z * vv[j].z + pv[i].w * vv[j].w;
        }
    }
#pragma unroll
    for (int i = 0; i < 4; ++i) {
        float invl = 1.0f / lrow[tm + 16 * i];
        size_t orow = ((size_t)b * L + q0 + tm + 16 * i) * 1024 + h * 64;
#pragma unroll
        for (int j = 0; j < 4; ++j)
            out[orow + tn + 16 * j] = acc[i][j] * invl;
    }
}

// ---------------- cross-attention: window (seg-128, seg] over memory --------
__global__ __launch_bounds__(256) void cross_attn_k(
    const float* __restrict__ qc, const float* __restrict__ kv,
    const int* __restrict__ seg_ids, float* __restrict__ out, int L, int S) {
    int l = blockIdx.x, h = blockIdx.y, b = blockIdx.z;
    __shared__ float qs[64];
    __shared__ float sc[LOOKBACK];
    __shared__ float red[4];
    __shared__ float pv[4][64];
    int tid = threadIdx.x;
    int seg = seg_ids[(size_t)b * L + l];
    int k0 = seg - LOOKBACK + 1; if (k0 < 0) k0 = 0;
    int nk = seg - k0 + 1;  // <= 128
    if (tid < 64) qs[tid] = qc[((size_t)b * L + l) * 1024 + h * 64 + tid];
    __syncthreads();
    float lmax = -1e30f;
    if (tid < nk) {
        int k = k0 + tid;
        const float* kr = kv + ((size_t)b * S + k) * 2048 + h * 64;
        float s = 0.f;
#pragma unroll
        for (int d = 0; d < 64; d += 4) {
            float4 k4 = *(const float4*)(kr + d);
            s += qs[d] * k4.x + qs[d + 1] * k4.y + qs[d + 2] * k4.z + qs[d + 3] * k4.w;
        }
        s *= 0.125f;
        sc[tid] = s;
        lmax = s;
    }
    float gmax = blk_max(lmax, red);
    float lsum = 0.f;
    if (tid < nk) {
        float p = __expf(sc[tid] - gmax);
        sc[tid] = p;
        lsum = p;
    }
    float gsum = blk_sum(lsum, red);
    float inv = 1.0f / gsum;
    int d = tid & 63, part = tid >> 6;
    float acc = 0.f;
    for (int kk = part; kk < nk; kk += 4)
        acc += sc[kk] * kv[((size_t)b * S + k0 + kk) * 2048 + 1024 + h * 64 + d];
    pv[part][d] = acc;
    __syncthreads();
    if (tid < 64) {
        float r = (pv[0][tid] + pv[1][tid] + pv[2][tid] + pv[3][tid]) * inv;
        out[((size_t)b * L + l) * 1024 + h * 64 + tid] = r;
    }
}

// ---------------- driver ----------------
extern "C" void kernel_launch(void* const* d_in, const int* in_sizes, int n_in,
                              void* d_out, int out_size, void* d_ws, size_t ws_size,
                              hipStream_t stream) {
    const int B = 2, L = 2048, S = 256, D = 1024, F = 4096;
    const int BL = B * L;
    const float* x_in   = (const float*)d_in[0];
    const float* memory = (const float*)d_in[1];
    const int*   seg    = (const int*)d_in[2];
    const float* Wqkv = (const float*)d_in[3];
    const float* bqkv = (const float*)d_in[4];
    const float* Wo   = (const float*)d_in[5];
    const float* bo   = (const float*)d_in[6];
    const float* Wq_c = (const float*)d_in[7];
    const float* Wkv_c= (const float*)d_in[8];
    const float* Wo_c = (const float*)d_in[9];
    const float* Wg   = (const float*)d_in[10];
    const float* Wu   = (const float*)d_in[11];
    const float* Wd   = (const float*)d_in[12];
    const float* n1   = (const float*)d_in[13];
    const float* n2   = (const float*)d_in[14];
    const float* n3   = (const float*)d_in[15];
    const float* nf   = (const float*)d_in[16];

    float* ws = (float*)d_ws;
    size_t off = 0;
    float* X   = ws + off; off += (size_t)BL * D;
    float* Hb  = ws + off; off += (size_t)BL * D;
    float* Att = ws + off; off += (size_t)BL * D;
    float* KVC = ws + off; off += (size_t)B * S * 2 * D;
    float* BIG = ws + off; off += (size_t)BL * F;  // QKV (BL*3D) aliases G (BL*F)
    float* QKV = BIG;
    float* G   = BIG;

    hipMemcpyAsync(X, x_in, (size_t)BL * D * sizeof(float), hipMemcpyDeviceToDevice, stream);

    dim3 blk(256);
    for (int l = 0; l < N_LAYERS; ++l) {
        // ---- self-attention block ----
        rmsnorm_k<<<BL, blk, 0, stream>>>(X, n1 + (size_t)l * D, Hb, D);
        gemm_nt<<<dim3(3 * D / 64, BL / 64), blk, 0, stream>>>(
            Hb, Wqkv + (size_t)l * 3 * D * D, QKV, bqkv + (size_t)l * 3 * D,
            nullptr, nullptr, BL, 3 * D, D);
        int total = BL * NHEADS * 32;
        rope_k<<<(total + 255) / 256, blk, 0, stream>>>(QKV, L, total);
        self_attn_flash<<<dim3(L / 64, NHEADS, B), blk, 0, stream>>>(QKV, Att, L);
        gemm_nt<<<dim3(D / 64, BL / 64), blk, 0, stream>>>(
            Att, Wo + (size_t)l * D * D, X, bo + (size_t)l * D, X, nullptr, BL, D, D);
        // ---- cross-attention block ----
        rmsnorm_k<<<BL, blk, 0, stream>>>(X, n2 + (size_t)l * D, Hb, D);
        gemm_nt<<<dim3(D / 64, BL / 64), blk, 0, stream>>>(
            Hb, Wq_c + (size_t)l * D * D, Att, nullptr, nullptr, nullptr, BL, D, D);
        gemm_nt<<<dim3(2 * D / 64, B * S / 64), blk, 0, stream>>>(
            memory, Wkv_c + (size_t)l * 2 * D * D, KVC, nullptr, nullptr, nullptr, B * S, 2 * D, D);
        cross_attn_k<<<dim3(L, NHEADS, B), blk, 0, stream>>>(Att, KVC, seg, Hb, L, S);
        gemm_nt<<<dim3(D / 64, BL / 64), blk, 0, stream>>>(
            Hb, Wo_c + (size_t)l * D * D, X, nullptr, X, nullptr, BL, D, D);
        // ---- MLP (SwiGLU) ----
        rmsnorm_k<<<BL, blk, 0, stream>>>(X, n3 + (size_t)l * D, Hb, D);
        gemm_nt<<<dim3(F / 64, BL / 64), blk, 0, stream>>>(
            Hb, Wg + (size_t)l * F * D, G, nullptr, nullptr, nullptr, BL, F, D);
        gemm_nt<<<dim3(F / 64, BL / 64), blk, 0, stream>>>(
            Hb, Wu + (size_t)l * F * D, G, nullptr, nullptr, G, BL, F, D);
        gemm_nt<<<dim3(D / 64, BL / 64), blk, 0, stream>>>(
            G, Wd + (size_t)l * D * F, X, nullptr, X, nullptr, BL, D, F);
    }
    rmsnorm_k<<<BL, blk, 0, stream>>>(X, nf, (float*)d_out, D);
}

// Round 4
// 6473.228 us; speedup vs baseline: 3.9548x; 2.2777x over previous
//
#include <hip/hip_runtime.h>
#include <hip/hip_bf16.h>
#include <math.h>

#define N_LAYERS 4
#define NHEADS 16
#define LOOKBACK 128

typedef unsigned short ushort_t;
typedef __attribute__((ext_vector_type(8))) short short8;
typedef __attribute__((ext_vector_type(4))) float f32x4;

__device__ __forceinline__ ushort_t f2bf(float f) {
    union { float f; unsigned int u; } v; v.f = f;
    unsigned int r = (v.u + 0x7FFFu + ((v.u >> 16) & 1u)) >> 16;
    return (ushort_t)r;
}
__device__ __forceinline__ float bf2f(ushort_t s) {
    union { unsigned int u; float f; } v; v.u = ((unsigned int)s) << 16;
    return v.f;
}

// ---------------- block reductions (blockDim == 256, 4 waves) ----------------
__device__ __forceinline__ float blk_max(float v, volatile float* red) {
#pragma unroll
    for (int o = 32; o > 0; o >>= 1) v = fmaxf(v, __shfl_down(v, o, 64));
    if ((threadIdx.x & 63) == 0) red[threadIdx.x >> 6] = v;
    __syncthreads();
    float r = fmaxf(fmaxf(red[0], red[1]), fmaxf(red[2], red[3]));
    __syncthreads();
    return r;
}
__device__ __forceinline__ float blk_sum(float v, volatile float* red) {
#pragma unroll
    for (int o = 32; o > 0; o >>= 1) v += __shfl_down(v, o, 64);
    if ((threadIdx.x & 63) == 0) red[threadIdx.x >> 6] = v;
    __syncthreads();
    float r = red[0] + red[1] + red[2] + red[3];
    __syncthreads();
    return r;
}

// ---------------- fp32 -> bf16 convert ----------------
__global__ __launch_bounds__(256) void f2b_k(const float* __restrict__ in,
                                             ushort_t* __restrict__ out, int n4) {
    int i = blockIdx.x * 256 + threadIdx.x;
    if (i >= n4) return;
    float4 v = *(const float4*)(in + (size_t)i * 4);
    ushort_t* o = out + (size_t)i * 4;
    o[0] = f2bf(v.x); o[1] = f2bf(v.y); o[2] = f2bf(v.z); o[3] = f2bf(v.w);
}

// ---------------- RMSNorm -> bf16 out ----------------
__global__ __launch_bounds__(256) void rmsnorm_bf(const float* __restrict__ x,
                                                  const float* __restrict__ w,
                                                  ushort_t* __restrict__ out, int D) {
    __shared__ float red[4];
    size_t row = blockIdx.x;
    const float* xr = x + row * D;
    float ss = 0.f;
    for (int i = threadIdx.x; i < D; i += 256) { float v = xr[i]; ss += v * v; }
    float tot = blk_sum(ss, red);
    float r = rsqrtf(tot / (float)D + 1e-6f);
    ushort_t* o = out + row * D;
    for (int i = threadIdx.x; i < D; i += 256) o[i] = f2bf(xr[i] * r * w[i]);
}

// ---------------- RMSNorm -> fp32 out (final) ----------------
__global__ __launch_bounds__(256) void rmsnorm_k(const float* __restrict__ x,
                                                 const float* __restrict__ w,
                                                 float* __restrict__ out, int D) {
    __shared__ float red[4];
    size_t row = blockIdx.x;
    const float* xr = x + row * D;
    float ss = 0.f;
    for (int i = threadIdx.x; i < D; i += 256) { float v = xr[i]; ss += v * v; }
    float tot = blk_sum(ss, red);
    float r = rsqrtf(tot / (float)D + 1e-6f);
    float* o = out + row * D;
    for (int i = threadIdx.x; i < D; i += 256) o[i] = xr[i] * r * w[i];
}

// ---------------- bf16 MFMA NT-GEMM (m97 structure) ----------------
// C[m,n] = sum_k A[m,k] * W[n,k]; A,W bf16 row-major; acc fp32.
// 128x128 tile, BK=32, 4 waves, each wave 64x64 via 4x4 mfma_16x16x32.
#define GBM 128
#define GBN 128
#define GBK 32

__global__ __launch_bounds__(256) void gemm_bf16(
    const ushort_t* __restrict__ A, const ushort_t* __restrict__ Bw,
    void* __restrict__ Cout, const float* __restrict__ bias,
    const float* __restrict__ resid, const ushort_t* __restrict__ gate,
    int M, int N, int K, int out_bf16) {
    __shared__ ushort_t As[GBM * GBK];
    __shared__ ushort_t Bs[GBN * GBK];
    int tid = threadIdx.x;
    int wave = tid >> 6, lane = tid & 63;
    int bm = blockIdx.y * GBM, bn = blockIdx.x * GBN;
    int wm = (wave & 1) * 64, wn = (wave >> 1) * 64;
    int r4 = lane >> 2, c4 = lane & 3;        // staging: row-in-16, 16B chunk
    int r = lane & 15, q = lane >> 4;         // mfma lane decomposition

    f32x4 acc[4][4];
#pragma unroll
    for (int i = 0; i < 4; ++i)
#pragma unroll
        for (int j = 0; j < 4; ++j) acc[i][j] = (f32x4){0.f, 0.f, 0.f, 0.f};

    int srow = wave * 16 + r4;
    for (int k0 = 0; k0 < K; k0 += GBK) {
        const ushort_t* Ag = A + (size_t)(bm + srow) * K + k0 + c4 * 8;
        const ushort_t* Bg = Bw + (size_t)(bn + srow) * K + k0 + c4 * 8;
        // dest = wave-uniform base; HW scatters lane i to base + i*16B,
        // i.e. row base/GBK + (lane>>2), chunk (lane&3)*8 elements.
        __builtin_amdgcn_global_load_lds(
            (const __attribute__((address_space(1))) void*)Ag,
            (__attribute__((address_space(3))) void*)&As[wave * 16 * GBK],
            16, 0, 0);
        __builtin_amdgcn_global_load_lds(
            (const __attribute__((address_space(1))) void*)(Ag + (size_t)64 * K),
            (__attribute__((address_space(3))) void*)&As[(64 + wave * 16) * GBK],
            16, 0, 0);
        __builtin_amdgcn_global_load_lds(
            (const __attribute__((address_space(1))) void*)Bg,
            (__attribute__((address_space(3))) void*)&Bs[wave * 16 * GBK],
            16, 0, 0);
        __builtin_amdgcn_global_load_lds(
            (const __attribute__((address_space(1))) void*)(Bg + (size_t)64 * K),
            (__attribute__((address_space(3))) void*)&Bs[(64 + wave * 16) * GBK],
            16, 0, 0);
        __syncthreads();
        short8 af[4], bfr[4];
#pragma unroll
        for (int i = 0; i < 4; ++i)
            af[i] = *(const short8*)&As[(wm + 16 * i + r) * GBK + q * 8];
#pragma unroll
        for (int j = 0; j < 4; ++j)
            bfr[j] = *(const short8*)&Bs[(wn + 16 * j + r) * GBK + q * 8];
#pragma unroll
        for (int i = 0; i < 4; ++i)
#pragma unroll
            for (int j = 0; j < 4; ++j)
                acc[i][j] = __builtin_amdgcn_mfma_f32_16x16x32_bf16(
                    af[i], bfr[j], acc[i][j], 0, 0, 0);
        __syncthreads();
    }
    // epilogue: row = bm+wm+16i+q*4+t, col = bn+wn+16j+r
#pragma unroll
    for (int i = 0; i < 4; ++i) {
#pragma unroll
        for (int j = 0; j < 4; ++j) {
            size_t n = (size_t)(bn + wn + 16 * j + r);
            float bn_v = bias ? bias[n] : 0.f;
#pragma unroll
            for (int t = 0; t < 4; ++t) {
                size_t m = (size_t)(bm + wm + 16 * i + q * 4 + t);
                size_t idx = m * N + n;
                float x = acc[i][j][t] + bn_v;
                if (gate) { float g = bf2f(gate[idx]); x *= g / (1.0f + __expf(-g)); }
                if (resid) x += resid[idx];
                if (out_bf16) ((ushort_t*)Cout)[idx] = f2bf(x);
                else ((float*)Cout)[idx] = x;
            }
        }
    }
}

// ---------------- RoPE in place on q and k of qkv buffer (fp32) -------------
__global__ void rope_k(float* __restrict__ qkv, int L, int total) {
    int idx = blockIdx.x * 256 + threadIdx.x;
    if (idx >= total) return;
    int d = idx & 31;
    int h = (idx >> 5) & 15;
    int bl = idx >> 9;
    int l = bl % L;
    float inv = powf(10000.0f, -(float)d * (1.0f / 32.0f));
    float f = (float)l * inv;
    float s, c;
    sincosf(f, &s, &c);
    float* base = qkv + (size_t)bl * 3072 + h * 64 + d;
    float x1 = base[0], x2 = base[32];
    base[0] = x1 * c - x2 * s;
    base[32] = x2 * c + x1 * s;
    float* kb = base + 1024;
    x1 = kb[0]; x2 = kb[32];
    kb[0] = x1 * c - x2 * s;
    kb[32] = x2 * c + x1 * s;
}

// ---------------- flash self-attention: 64q x 64k tiles, bf16 out -----------
#define SPAD 68

__global__ __launch_bounds__(256) void self_attn_flash(
    const float* __restrict__ qkv, ushort_t* __restrict__ out, int L) {
    int qt = blockIdx.x, h = blockIdx.y, b = blockIdx.z;
    int q0 = qt * 64;
    __shared__ float Qs[64][SPAD];
    __shared__ float Ks[64][SPAD];
    __shared__ float VsT[64][SPAD];
    __shared__ float Ss[64][SPAD];
    __shared__ float mrow[64], lrow[64], arow[64];
    int tid = threadIdx.x;
    int lr = tid >> 2;
    int lc = tid & 3;
    {
        const float* src = qkv + ((size_t)b * L + q0 + lr) * 3072 + h * 64;
#pragma unroll
        for (int t = 0; t < 4; ++t) {
            int c = (lc + t * 4) * 4;
            float4 v = *(const float4*)(src + c);
            Qs[lr][c + 0] = v.x * 0.125f; Qs[lr][c + 1] = v.y * 0.125f;
            Qs[lr][c + 2] = v.z * 0.125f; Qs[lr][c + 3] = v.w * 0.125f;
        }
    }
    if (tid < 64) { mrow[tid] = -1e30f; lrow[tid] = 0.f; }
    int tm = tid >> 4;
    int tn = tid & 15;
    float acc[4][4] = {};
    for (int kt = 0; kt <= qt; ++kt) {
        int k0 = kt * 64;
        __syncthreads();
        {
            const float* ksrc = qkv + ((size_t)b * L + k0 + lr) * 3072 + 1024 + h * 64;
            const float* vsrc = ksrc + 1024;
#pragma unroll
            for (int t = 0; t < 4; ++t) {
                int c = (lc + t * 4) * 4;
                float4 kv4 = *(const float4*)(ksrc + c);
                Ks[lr][c + 0] = kv4.x; Ks[lr][c + 1] = kv4.y;
                Ks[lr][c + 2] = kv4.z; Ks[lr][c + 3] = kv4.w;
                float4 vv4 = *(const float4*)(vsrc + c);
                VsT[c + 0][lr] = vv4.x; VsT[c + 1][lr] = vv4.y;
                VsT[c + 2][lr] = vv4.z; VsT[c + 3][lr] = vv4.w;
            }
        }
        __syncthreads();
        float s[4][4] = {};
        for (int k4 = 0; k4 < 64; k4 += 4) {
            float4 qv[4], kv[4];
#pragma unroll
            for (int i = 0; i < 4; ++i) qv[i] = *(const float4*)&Qs[tm + 16 * i][k4];
#pragma unroll
            for (int j = 0; j < 4; ++j) kv[j] = *(const float4*)&Ks[tn + 16 * j][k4];
#pragma unroll
            for (int i = 0; i < 4; ++i)
#pragma unroll
                for (int j = 0; j < 4; ++j)
                    s[i][j] += qv[i].x * kv[j].x + qv[i].y * kv[j].y +
                               qv[i].z * kv[j].z + qv[i].w * kv[j].w;
        }
        bool diag = (kt == qt);
#pragma unroll
        for (int i = 0; i < 4; ++i)
#pragma unroll
            for (int j = 0; j < 4; ++j) {
                float v = s[i][j];
                if (diag && (tn + 16 * j > tm + 16 * i)) v = -1e30f;
                Ss[tm + 16 * i][tn + 16 * j] = v;
            }
        __syncthreads();
        if (tid < 64) {
            float mold = mrow[tid];
            float mx = mold;
            float* srow = &Ss[tid][0];
            for (int c = 0; c < 64; c += 4) {
                float4 v = *(const float4*)(srow + c);
                mx = fmaxf(mx, fmaxf(fmaxf(v.x, v.y), fmaxf(v.z, v.w)));
            }
            float al = __expf(mold - mx);
            float sum = 0.f;
            for (int c = 0; c < 64; c += 4) {
                float4 v = *(const float4*)(srow + c);
                v.x = __expf(v.x - mx); v.y = __expf(v.y - mx);
                v.z = __expf(v.z - mx); v.w = __expf(v.w - mx);
                sum += v.x + v.y + v.z + v.w;
                *(float4*)(srow + c) = v;
            }
            mrow[tid] = mx;
            lrow[tid] = lrow[tid] * al + sum;
            arow[tid] = al;
        }
        __syncthreads();
#pragma unroll
        for (int i = 0; i < 4; ++i) {
            float al = arow[tm + 16 * i];
#pragma unroll
            for (int j = 0; j < 4; ++j) acc[i][j] *= al;
        }
        for (int k4 = 0; k4 < 64; k4 += 4) {
            float4 pv[4], vv[4];
#pragma unroll
            for (int i = 0; i < 4; ++i) pv[i] = *(const float4*)&Ss[tm + 16 * i][k4];
#pragma unroll
            for (int j = 0; j < 4; ++j) vv[j] = *(const float4*)&VsT[tn + 16 * j][k4];
#pragma unroll
            for (int i = 0; i < 4; ++i)
#pragma unroll
                for (int j = 0; j < 4; ++j)
                    acc[i][j] += pv[i].x * vv[j].x + pv[i].y * vv[j].y +
                                 pv[i].z * vv[j].z + pv[i].w * vv[j].w;
        }
    }
#pragma unroll
    for (int i = 0; i < 4; ++i) {
        float invl = 1.0f / lrow[tm + 16 * i];
        size_t orow = ((size_t)b * L + q0 + tm + 16 * i) * 1024 + h * 64;
#pragma unroll
        for (int j = 0; j < 4; ++j)
            out[orow + tn + 16 * j] = f2bf(acc[i][j] * invl);
    }
}

// ---------------- cross-attention, bf16 out ----------------
__global__ __launch_bounds__(256) void cross_attn_k(
    const float* __restrict__ qc, const float* __restrict__ kv,
    const int* __restrict__ seg_ids, ushort_t* __restrict__ out, int L, int S) {
    int l = blockIdx.x, h = blockIdx.y, b = blockIdx.z;
    __shared__ float qs[64];
    __shared__ float sc[LOOKBACK];
    __shared__ float red[4];
    __shared__ float pv[4][64];
    int tid = threadIdx.x;
    int seg = seg_ids[(size_t)b * L + l];
    int k0 = seg - LOOKBACK + 1; if (k0 < 0) k0 = 0;
    int nk = seg - k0 + 1;
    if (tid < 64) qs[tid] = qc[((size_t)b * L + l) * 1024 + h * 64 + tid];
    __syncthreads();
    float lmax = -1e30f;
    if (tid < nk) {
        int k = k0 + tid;
        const float* kr = kv + ((size_t)b * S + k) * 2048 + h * 64;
        float s = 0.f;
#pragma unroll
        for (int d = 0; d < 64; d += 4) {
            float4 k4 = *(const float4*)(kr + d);
            s += qs[d] * k4.x + qs[d + 1] * k4.y + qs[d + 2] * k4.z + qs[d + 3] * k4.w;
        }
        s *= 0.125f;
        sc[tid] = s;
        lmax = s;
    }
    float gmax = blk_max(lmax, red);
    float lsum = 0.f;
    if (tid < nk) {
        float p = __expf(sc[tid] - gmax);
        sc[tid] = p;
        lsum = p;
    }
    float gsum = blk_sum(lsum, red);
    float inv = 1.0f / gsum;
    int d = tid & 63, part = tid >> 6;
    float acc = 0.f;
    for (int kk = part; kk < nk; kk += 4)
        acc += sc[kk] * kv[((size_t)b * S + k0 + kk) * 2048 + 1024 + h * 64 + d];
    pv[part][d] = acc;
    __syncthreads();
    if (tid < 64) {
        float r = (pv[0][tid] + pv[1][tid] + pv[2][tid] + pv[3][tid]) * inv;
        out[((size_t)b * L + l) * 1024 + h * 64 + tid] = f2bf(r);
    }
}

// ---------------- driver ----------------
extern "C" void kernel_launch(void* const* d_in, const int* in_sizes, int n_in,
                              void* d_out, int out_size, void* d_ws, size_t ws_size,
                              hipStream_t stream) {
    const int B = 2, L = 2048, S = 256, D = 1024, F = 4096;
    const int BL = B * L;
    const float* x_in   = (const float*)d_in[0];
    const float* memory = (const float*)d_in[1];
    const int*   seg    = (const int*)d_in[2];
    const float* Wqkv = (const float*)d_in[3];
    const float* bqkv = (const float*)d_in[4];
    const float* Wo   = (const float*)d_in[5];
    const float* bo   = (const float*)d_in[6];
    const float* Wq_c = (const float*)d_in[7];
    const float* Wkv_c= (const float*)d_in[8];
    const float* Wo_c = (const float*)d_in[9];
    const float* Wg   = (const float*)d_in[10];
    const float* Wu   = (const float*)d_in[11];
    const float* Wd   = (const float*)d_in[12];
    const float* n1   = (const float*)d_in[13];
    const float* n2   = (const float*)d_in[14];
    const float* n3   = (const float*)d_in[15];
    const float* nf   = (const float*)d_in[16];

    char* ws = (char*)d_ws;
    size_t off = 0;
    float* X     = (float*)(ws + off); off += (size_t)BL * D * 4;        // 16 MB
    float* QKV   = (float*)(ws + off); off += (size_t)BL * 3 * D * 4;    // 48 MB (aliases Qc, Gg)
    float* KVC   = (float*)(ws + off); off += (size_t)B * S * 2 * D * 4; // 4 MB
    ushort_t* Hn  = (ushort_t*)(ws + off); off += (size_t)BL * D * 2;    // 8 MB
    ushort_t* Abf = (ushort_t*)(ws + off); off += (size_t)BL * D * 2;    // 8 MB
    ushort_t* Mb  = (ushort_t*)(ws + off); off += (size_t)B * S * D * 2; // 1 MB
    ushort_t* Wb  = (ushort_t*)(ws + off); off += (size_t)F * D * 2;     // 8 MB
    float* Qc = QKV;                    // fp32 view, cross phase
    ushort_t* Gg = (ushort_t*)QKV;      // bf16 view, MLP phase

    hipMemcpyAsync(X, x_in, (size_t)BL * D * sizeof(float), hipMemcpyDeviceToDevice, stream);

    dim3 blk(256);
    // memory -> bf16 once
    f2b_k<<<(B * S * D / 4 + 255) / 256, blk, 0, stream>>>(memory, Mb, B * S * D / 4);

    for (int l = 0; l < N_LAYERS; ++l) {
        // ---- self-attention block ----
        rmsnorm_bf<<<BL, blk, 0, stream>>>(X, n1 + (size_t)l * D, Hn, D);
        f2b_k<<<(3 * D * D / 4 + 255) / 256, blk, 0, stream>>>(
            Wqkv + (size_t)l * 3 * D * D, Wb, 3 * D * D / 4);
        gemm_bf16<<<dim3(3 * D / GBN, BL / GBM), blk, 0, stream>>>(
            Hn, Wb, QKV, bqkv + (size_t)l * 3 * D, nullptr, nullptr, BL, 3 * D, D, 0);
        int total = BL * NHEADS * 32;
        rope_k<<<(total + 255) / 256, blk, 0, stream>>>(QKV, L, total);
        self_attn_flash<<<dim3(L / 64, NHEADS, B), blk, 0, stream>>>(QKV, Abf, L);
        f2b_k<<<(D * D / 4 + 255) / 256, blk, 0, stream>>>(
            Wo + (size_t)l * D * D, Wb, D * D / 4);
        gemm_bf16<<<dim3(D / GBN, BL / GBM), blk, 0, stream>>>(
            Abf, Wb, X, bo + (size_t)l * D, X, nullptr, BL, D, D, 0);
        // ---- cross-attention block ----
        rmsnorm_bf<<<BL, blk, 0, stream>>>(X, n2 + (size_t)l * D, Hn, D);
        f2b_k<<<(D * D / 4 + 255) / 256, blk, 0, stream>>>(
            Wq_c + (size_t)l * D * D, Wb, D * D / 4);
        gemm_bf16<<<dim3(D / GBN, BL / GBM), blk, 0, stream>>>(
            Hn, Wb, Qc, nullptr, nullptr, nullptr, BL, D, D, 0);
        f2b_k<<<(2 * D * D / 4 + 255) / 256, blk, 0, stream>>>(
            Wkv_c + (size_t)l * 2 * D * D, Wb, 2 * D * D / 4);
        gemm_bf16<<<dim3(2 * D / GBN, B * S / GBM), blk, 0, stream>>>(
            Mb, Wb, KVC, nullptr, nullptr, nullptr, B * S, 2 * D, D, 0);
        cross_attn_k<<<dim3(L, NHEADS, B), blk, 0, stream>>>(Qc, KVC, seg, Abf, L, S);
        f2b_k<<<(D * D / 4 + 255) / 256, blk, 0, stream>>>(
            Wo_c + (size_t)l * D * D, Wb, D * D / 4);
        gemm_bf16<<<dim3(D / GBN, BL / GBM), blk, 0, stream>>>(
            Abf, Wb, X, nullptr, X, nullptr, BL, D, D, 0);
        // ---- MLP (SwiGLU) ----
        rmsnorm_bf<<<BL, blk, 0, stream>>>(X, n3 + (size_t)l * D, Hn, D);
        f2b_k<<<(F * D / 4 + 255) / 256, blk, 0, stream>>>(
            Wg + (size_t)l * F * D, Wb, F * D / 4);
        gemm_bf16<<<dim3(F / GBN, BL / GBM), blk, 0, stream>>>(
            Hn, Wb, Gg, nullptr, nullptr, nullptr, BL, F, D, 1);
        f2b_k<<<(F * D / 4 + 255) / 256, blk, 0, stream>>>(
            Wu + (size_t)l * F * D, Wb, F * D / 4);
        gemm_bf16<<<dim3(F / GBN, BL / GBM), blk, 0, stream>>>(
            Hn, Wb, Gg, nullptr, nullptr, Gg, BL, F, D, 1);   // silu(g)*u in place
        f2b_k<<<(D * F / 4 + 255) / 256, blk, 0, stream>>>(
            Wd + (size_t)l * D * F, Wb, D * F / 4);
        gemm_bf16<<<dim3(D / GBN, BL / GBM), blk, 0, stream>>>(
            Gg, Wb, X, nullptr, X, nullptr, BL, D, F, 0);
    }
    rmsnorm_k<<<BL, blk, 0, stream>>>(X, nf, (float*)d_out, D);
}